// Round 6
// baseline (814.862 us; speedup 1.0000x reference)
//
#include <hip/hip_runtime.h>
#include <stdint.h>

// Problem constants (fixed by reference)
#define NSRC 50000
#define NTGT 50000
#define NE   320000
#define DIN  256
#define HID  256
#define DOUT 16

#define GBM 64
#define GBLK ((NSRC + GBM - 1) / GBM)      // 782 gemm blocks

typedef __attribute__((ext_vector_type(8))) short bf16x8;
typedef __attribute__((ext_vector_type(4))) float f32x4;
typedef __attribute__((ext_vector_type(4))) uint u32x4;

// ---------------------------------------------------------------------------
// bf16 <-> f32 (RNE, matches HW/XLA rounding)
// ---------------------------------------------------------------------------
__device__ inline ushort f2b(float f) {
  uint32_t u = __float_as_uint(f);
  return (ushort)((u + 0x7FFFu + ((u >> 16) & 1u)) >> 16);
}
__device__ inline float b2f(ushort h) { return __uint_as_float(((uint32_t)h) << 16); }

// ---------------------------------------------------------------------------
// Async global->LDS 16B copy: lane deposits 16 B at lds_base + lane*16.
// ---------------------------------------------------------------------------
typedef __attribute__((address_space(3))) uint32_t lds_u32_t;
typedef const __attribute__((address_space(1))) uint32_t glb_u32_t;
__device__ __forceinline__ void ld_lds16(const ushort* g, ushort* lds) {
  __builtin_amdgcn_global_load_lds((glb_u32_t*)g, (lds_u32_t*)lds, 16, 0, 0);
}

// ---------------------------------------------------------------------------
// Threefry-2x32 (exact JAX: 20 rounds, 5 key injections) — verified R2
// ---------------------------------------------------------------------------
__host__ __device__ constexpr uint64_t tf2x32(uint32_t k0, uint32_t k1,
                                              uint32_t x0, uint32_t x1) {
  uint32_t ks2 = k0 ^ k1 ^ 0x1BD11BDAu;
  x0 += k0; x1 += k1;
#define TF_ROT(x, r) (((x) << (r)) | ((x) >> (32 - (r))))
#define TF_RND(r) { x0 += x1; x1 = TF_ROT(x1, r) ^ x0; }
  TF_RND(13) TF_RND(15) TF_RND(26) TF_RND(6)
  x0 += k1;  x1 += ks2 + 1u;
  TF_RND(17) TF_RND(29) TF_RND(16) TF_RND(24)
  x0 += ks2; x1 += k0 + 2u;
  TF_RND(13) TF_RND(15) TF_RND(26) TF_RND(6)
  x0 += k0;  x1 += k1 + 3u;
  TF_RND(17) TF_RND(29) TF_RND(16) TF_RND(24)
  x0 += k1;  x1 += ks2 + 4u;
  TF_RND(13) TF_RND(15) TF_RND(26) TF_RND(6)
  x0 += ks2; x1 += k0 + 5u;
#undef TF_RND
#undef TF_ROT
  return (uint64_t(x0) << 32) | uint64_t(x1);
}

constexpr uint64_t FOLD[4] = {
  tf2x32(0u, 42u, 0u, 0u),
  tf2x32(0u, 42u, 0u, 1u),
  tf2x32(0u, 42u, 0u, 2u),
  tf2x32(0u, 42u, 0u, 3u),
};

// ---------------------------------------------------------------------------
// Inline dropout keep-mask pair for (gemm g, block bid, thread tid).
// Bit-for-bit identical to the old precomputed mask_word(d) for
// d = g*MASK + bid*512 + tid*2 (+1): same tf2x32 inputs, same keep rule
// (bits>>9 < 7549747 == 0.9f*2^23 exact), same bit positions.
// ---------------------------------------------------------------------------
__device__ __forceinline__ uint2 mask_pair(int g, int bid, int wave, int q, int r) {
  uint64_t fk = (g == 0) ? FOLD[1] : (g == 1 ? FOLD[0] : FOLD[2]);
  uint32_t kk0 = (uint32_t)(fk >> 32), kk1 = (uint32_t)fk;
  int mbase = bid * GBM;
  uint32_t kmx = 0, kmy = 0;
#pragma unroll 2
  for (int s = 0; s < 64; ++s) {
    int si = s >> 4, se = (s >> 2) & 3, sj = s & 3;
    uint32_t rowg = (uint32_t)(mbase + si * 16 + q * 4 + se);
    uint32_t colg = (uint32_t)(wave * 64 + sj * 16 + r);
    uint64_t rr = tf2x32(kk0, kk1, 0u, rowg * 256u + colg);
    uint32_t bits = (uint32_t)(rr >> 32) ^ (uint32_t)rr;
    uint32_t b = ((bits >> 9) < 7549747u) ? 1u : 0u;
    if (s < 32) kmx |= b << s;
    else        kmy |= b << (s - 32);
  }
  uint2 km; km.x = kmx; km.y = kmy;
  return km;
}

// ---------------------------------------------------------------------------
// prep_kernel: independent front work:
//   [0, 25000)        f32->bf16 conversion of both inputs  (memory-bound)
//   [25000, 25096)    6 weight transpose+converts           (memory-bound)
//   [25096, 27596)    2 CSR histograms                      (atomic-bound)
// ---------------------------------------------------------------------------
#define NB_CVT  25000
#define NB_W    96
#define NB_HIST 2500
#define PREP_T  (NB_CVT + NB_W + NB_HIST)  // 27596

struct PrepArgs {
  const float *xs, *xt;
  ushort *oxs, *oxt;
  const float* wsrc[6];
  ushort* wdst[6];
  const int *ei_a, *ei_b;
  int *cur_a, *cur_b;
};

__global__ __launch_bounds__(256) void prep_kernel(PrepArgs p) {
  __shared__ ushort tile[64][65];
  int blk = (int)(((long long)blockIdx.x * 97) % PREP_T);
  int tid = threadIdx.x;
  if (blk < NB_CVT) {  // input conversion
    const float* in = blk < (NB_CVT / 2) ? p.xs : p.xt;
    ushort* out = blk < (NB_CVT / 2) ? p.oxs : p.oxt;
    int i = (blk % (NB_CVT / 2)) * 256 + tid;
    float4 v = ((const float4*)in)[i];
    ushort4 o;
    o.x = f2b(v.x); o.y = f2b(v.y); o.z = f2b(v.z); o.w = f2b(v.w);
    ((ushort4*)out)[i] = o;
    return;
  }
  blk -= NB_CVT;
  if (blk < NB_W) {  // weight transpose: fp32 [k][n] -> bf16 [n][k]
    const float* W = p.wsrc[blk >> 4];
    ushort* Wt = p.wdst[blk >> 4];
    int ktile = (blk >> 2) & 3, ntile = blk & 3;
#pragma unroll
    for (int rep = 0; rep < 16; ++rep) {
      int lin = rep * 256 + tid;
      int kk = lin >> 6, nn = lin & 63;
      tile[nn][kk] = f2b(W[(size_t)(ktile * 64 + kk) * 256 + ntile * 64 + nn]);
    }
    __syncthreads();
#pragma unroll
    for (int rep = 0; rep < 16; ++rep) {
      int lin = rep * 256 + tid;
      int nn = lin >> 6, kk = lin & 63;
      Wt[(size_t)(ntile * 64 + nn) * 256 + ktile * 64 + kk] = tile[nn][kk];
    }
    return;
  }
  blk -= NB_W;
  // CSR histogram
  const int* ei = blk < (NB_HIST / 2) ? p.ei_a : p.ei_b;
  int* cur = blk < (NB_HIST / 2) ? p.cur_a : p.cur_b;
  int e = (blk % (NB_HIST / 2)) * 256 + tid;
  if (e < NE) atomicAdd(cur + ei[NE + e], 1);
}

// ---------------------------------------------------------------------------
// CSR scan + fill (two-level scan, verified R6)
// ---------------------------------------------------------------------------
#define SB 1024
__global__ __launch_bounds__(SB) void scan_partial(const int* __restrict__ cur_a,
                                                   const int* __restrict__ cur_b,
                                                   int* __restrict__ bsum,
                                                   int n, int nbPer) {
  __shared__ int red[SB];
  int b = blockIdx.x;
  const int* cnt = b < nbPer ? cur_a : cur_b;
  int i = (b % nbPer) * SB + threadIdx.x;
  red[threadIdx.x] = (i < n) ? cnt[i] : 0;
  __syncthreads();
  for (int d = SB / 2; d > 0; d >>= 1) {
    if (threadIdx.x < d) red[threadIdx.x] += red[threadIdx.x + d];
    __syncthreads();
  }
  if (threadIdx.x == 0) bsum[b] = red[0];
}

__global__ __launch_bounds__(128) void scan_base(int* __restrict__ bsum, int nbPer) {
  __shared__ int buf[2][64];
  int half = threadIdx.x >> 6;
  int t = threadIdx.x & 63;
  buf[half][t] = (t < nbPer) ? bsum[half * nbPer + t] : 0;
  __syncthreads();
  for (int d = 1; d < 64; d <<= 1) {
    int v = (t >= d) ? buf[half][t - d] : 0;
    __syncthreads();
    buf[half][t] += v;
    __syncthreads();
  }
  if (t < nbPer) bsum[half * nbPer + t] = (t == 0) ? 0 : buf[half][t - 1];
}

__global__ __launch_bounds__(SB) void scan_final(int* __restrict__ cur_a,
                                                 int* __restrict__ cur_b,
                                                 int* __restrict__ offs_a,
                                                 int* __restrict__ offs_b,
                                                 const int* __restrict__ bsum,
                                                 int n, int nbPer) {
  __shared__ int part[SB];
  int b = blockIdx.x;
  bool first = b < nbPer;
  int* cur = first ? cur_a : cur_b;
  int* offs = first ? offs_a : offs_b;
  int i = (b % nbPer) * SB + threadIdx.x;
  int v = (i < n) ? cur[i] : 0;
  part[threadIdx.x] = v;
  __syncthreads();
  for (int d = 1; d < SB; d <<= 1) {
    int tv = (threadIdx.x >= d) ? part[threadIdx.x - d] : 0;
    __syncthreads();
    part[threadIdx.x] += tv;
    __syncthreads();
  }
  int excl = part[threadIdx.x] - v + bsum[b];
  if (i < n) {
    offs[i] = excl;
    cur[i] = 0;
  }
  if (i == n - 1) offs[n] = excl + v;
}

__global__ __launch_bounds__(256) void csr_fill2(const int* __restrict__ ei_a,
                                                 const int* __restrict__ ei_b,
                                                 const int* __restrict__ offs_a,
                                                 const int* __restrict__ offs_b,
                                                 int* __restrict__ cur_a,
                                                 int* __restrict__ cur_b,
                                                 int* __restrict__ adj_a,
                                                 int* __restrict__ adj_b,
                                                 int nE, int nbPer) {
  int blk = blockIdx.x;
  bool first = blk < nbPer;
  const int* ei = first ? ei_a : ei_b;
  const int* offs = first ? offs_a : offs_b;
  int* cur = first ? cur_a : cur_b;
  int* adj = first ? adj_a : adj_b;
  int e = (blk % nbPer) * 256 + threadIdx.x;
  if (e >= nE) return;
  int dst = ei[nE + e];
  int pos = atomicAdd(cur + dst, 1);
  adj[offs[dst] + pos] = ei[e];
}

// ---------------------------------------------------------------------------
// Segment-mean gather: 32 lanes per row (16B loads). Per-feature accumulation
// order = ascending edge order -> bit-identical to the original.
// ---------------------------------------------------------------------------
__device__ __forceinline__ void gather_row8(const ushort* x,
                                            const int* __restrict__ offs,
                                            const int* __restrict__ adj,
                                            ushort* m,
                                            int row, int lane) {  // lane 0..31
  int start = offs[row], end = offs[row + 1];
  float a0 = 0.f, a1 = 0.f, a2 = 0.f, a3 = 0.f;
  float a4 = 0.f, a5 = 0.f, a6 = 0.f, a7 = 0.f;
  const ushort* xb = x + lane * 8;
  int e = start;
  for (; e + 3 < end; e += 4) {
    int s0 = adj[e], s1 = adj[e + 1], s2 = adj[e + 2], s3 = adj[e + 3];
    u32x4 v0 = *(const u32x4*)(xb + (size_t)s0 * DIN);
    u32x4 v1 = *(const u32x4*)(xb + (size_t)s1 * DIN);
    u32x4 v2 = *(const u32x4*)(xb + (size_t)s2 * DIN);
    u32x4 v3 = *(const u32x4*)(xb + (size_t)s3 * DIN);
    const ushort* u;
    u = (const ushort*)&v0;
    a0 += b2f(u[0]); a1 += b2f(u[1]); a2 += b2f(u[2]); a3 += b2f(u[3]);
    a4 += b2f(u[4]); a5 += b2f(u[5]); a6 += b2f(u[6]); a7 += b2f(u[7]);
    u = (const ushort*)&v1;
    a0 += b2f(u[0]); a1 += b2f(u[1]); a2 += b2f(u[2]); a3 += b2f(u[3]);
    a4 += b2f(u[4]); a5 += b2f(u[5]); a6 += b2f(u[6]); a7 += b2f(u[7]);
    u = (const ushort*)&v2;
    a0 += b2f(u[0]); a1 += b2f(u[1]); a2 += b2f(u[2]); a3 += b2f(u[3]);
    a4 += b2f(u[4]); a5 += b2f(u[5]); a6 += b2f(u[6]); a7 += b2f(u[7]);
    u = (const ushort*)&v3;
    a0 += b2f(u[0]); a1 += b2f(u[1]); a2 += b2f(u[2]); a3 += b2f(u[3]);
    a4 += b2f(u[4]); a5 += b2f(u[5]); a6 += b2f(u[6]); a7 += b2f(u[7]);
  }
  for (; e < end; ++e) {
    int s = adj[e];
    u32x4 v = *(const u32x4*)(xb + (size_t)s * DIN);
    const ushort* u = (const ushort*)&v;
    a0 += b2f(u[0]); a1 += b2f(u[1]); a2 += b2f(u[2]); a3 += b2f(u[3]);
    a4 += b2f(u[4]); a5 += b2f(u[5]); a6 += b2f(u[6]); a7 += b2f(u[7]);
  }
  float inv = 1.0f / fmaxf((float)(end - start), 1.0f);
  ushort o[8];
  o[0] = f2b(a0 * inv); o[1] = f2b(a1 * inv); o[2] = f2b(a2 * inv); o[3] = f2b(a3 * inv);
  o[4] = f2b(a4 * inv); o[5] = f2b(a5 * inv); o[6] = f2b(a6 * inv); o[7] = f2b(a7 * inv);
  *(u32x4*)(m + (size_t)row * DIN + lane * 8) = *(const u32x4*)o;
}

// ---------------------------------------------------------------------------
// MFMA dual GEMM K-loop (verified R8-R10): acc = A1@W1 + A2@W2 (bf16 MFMA,
// f32 acc). Async global_load_lds staging; 40KB LDS footprint.
// ---------------------------------------------------------------------------
__device__ __forceinline__ void gemm_kloop(
    int bid, const ushort* A1, const ushort* __restrict__ A2,
    const ushort* __restrict__ W1t, const ushort* __restrict__ W2t,
    int M, ushort* sA, ushort* sB, f32x4 acc[4][4]) {
  const int tid = threadIdx.x;
  const int wave = tid >> 6, lane = tid & 63;
  const int q = lane >> 4, r = lane & 15;
  const int mbase = bid * GBM;

  const int arow = tid >> 2;        // 0..63
  const int akc = (tid & 3) * 8;    // short offset 0,8,16,24
  const int agrow = min(mbase + arow, M - 1);
  const ushort* a1p = A1 + (size_t)agrow * DIN + akc;
  const ushort* a2p = A2 + (size_t)agrow * DIN + akc;
  const ushort* w1b = W1t + (size_t)arow * DIN + akc;
  const ushort* w2b = W2t + (size_t)arow * DIN + akc;
  ushort* ldsA0 = sA + wave * 512;              // sA phase 0
  ushort* ldsA1 = sA + 2048 + wave * 512;       // sA phase 1

#pragma unroll
  for (int t = 0; t < 8; ++t) {
    const int kt = t * 32;
    __syncthreads();  // prior iter's LDS reads done before DMA overwrites
    ld_lds16(a1p + kt, ldsA0);
    ld_lds16(a2p + kt, ldsA1);
#pragma unroll
    for (int c = 0; c < 4; ++c) {
      ld_lds16(w1b + c * (64 * DIN) + kt, sB + c * 2048 + wave * 512);
      ld_lds16(w2b + c * (64 * DIN) + kt, sB + 8192 + c * 2048 + wave * 512);
    }
    __syncthreads();  // drains vmcnt(0): DMA complete
#pragma unroll
    for (int ph = 0; ph < 2; ++ph) {
      bf16x8 af[4], bfr[4];
#pragma unroll
      for (int i = 0; i < 4; ++i)
        af[i] = *(const bf16x8*)&sA[ph * 2048 + (i * 16 + r) * 32 + q * 8];
#pragma unroll
      for (int j = 0; j < 4; ++j)
        bfr[j] = *(const bf16x8*)&sB[ph * 8192 + (wave * 64 + j * 16 + r) * 32 + q * 8];
#pragma unroll
      for (int i = 0; i < 4; ++i)
#pragma unroll
        for (int j = 0; j < 4; ++j)
          acc[i][j] = __builtin_amdgcn_mfma_f32_16x16x32_bf16(af[i], bfr[j],
                                                              acc[i][j], 0, 0, 0);
    }
  }
}

// ---------------------------------------------------------------------------
// Fused gather+GEMM body (R12): block bid
//   1. gathers its own 64 A1-rows (seg-mean) -> bounce[rows] (global, block-
//      private rows; write -> __syncthreads -> DMA-read is L2-warm & coherent)
//   2. runs the verified K-loop with A1 = bounce
//   3. epilogue: inline threefry masks (bit-identical to precomputed),
//      bias + leaky + dropout -> C. bounce may equal C (disjoint in time:
//      all global A1 reads complete before the first epilogue store).
// ---------------------------------------------------------------------------
__device__ __forceinline__ void gemm_fused_body(
    int bid, int g, const ushort* gsrc,
    const int* __restrict__ goffs, const int* __restrict__ gadj,
    ushort* bounce, const ushort* __restrict__ A2,
    const ushort* __restrict__ W1t, const ushort* __restrict__ W2t,
    const float* __restrict__ bias, ushort* C, int M,
    ushort* sA, ushort* sB) {
  const int tid = threadIdx.x;
  const int wave = tid >> 6, lane = tid & 63;
  const int q = lane >> 4, r = lane & 15;
  const int mbase = bid * GBM;

  // Gather this block's 64 rows (8 passes x 8 rows, 32 lanes/row).
#pragma unroll
  for (int pass = 0; pass < 8; ++pass) {
    int row = mbase + pass * 8 + (tid >> 5);
    if (row < M) gather_row8(gsrc, goffs, gadj, bounce, row, tid & 31);
  }
  __syncthreads();  // drains vmcnt: bounce rows visible to DMA reads

  f32x4 acc[4][4] = {};
  gemm_kloop(bid, bounce, A2, W1t, W2t, M, sA, sB, acc);

  float bj[4];
#pragma unroll
  for (int j = 0; j < 4; ++j) bj[j] = bias[wave * 64 + j * 16 + r];

  const uint2 km = mask_pair(g, bid, wave, q, r);  // VALU; bias loads in flight

#pragma unroll
  for (int i = 0; i < 4; ++i) {
#pragma unroll
    for (int e = 0; e < 4; ++e) {
      int rowg = mbase + i * 16 + q * 4 + e;
      if (rowg >= M) continue;
#pragma unroll
      for (int j = 0; j < 4; ++j) {
        const int s = i * 16 + e * 4 + j;
        int colg = wave * 64 + j * 16 + r;
        float v = acc[i][j][e] + bj[j];
        v = v >= 0.0f ? v : 0.01f * v;
        uint32_t keep = ((s < 32 ? km.x >> s : km.y >> (s - 32)) & 1u);
        v = keep ? v * (1.0f / 0.9f) : 0.0f;
        C[(size_t)rowg * HID + colg] = f2b(v);
      }
    }
  }
}

// ---------------------------------------------------------------------------
// Launch A: gemm1_f (782) + gemm2_f (782), independent, one swizzled launch.
//   gemm1_f: m_t = gather_st(xs) -> bounce B2 rows -> t1 = ... -> B2 (self)
//   gemm2_f: m_s = gather_ts(xt) -> bounce B0 rows -> s1 = ... -> B0 (self)
// FA_T = 1564 = 2^2*17*23; 101 coprime.
// ---------------------------------------------------------------------------
#define FA_T (2 * GBLK)

__global__ __launch_bounds__(256, 4) void gemm_fused12(
    const ushort* __restrict__ xs, const ushort* __restrict__ xt,
    const int* __restrict__ offs_st, const int* __restrict__ adj_st,
    const int* __restrict__ offs_ts, const int* __restrict__ adj_ts,
    const ushort* __restrict__ wt0, const ushort* __restrict__ wt1,
    const ushort* __restrict__ wt2, const ushort* __restrict__ wt3,
    const float* __restrict__ b_st, const float* __restrict__ b_ts,
    ushort* B0, ushort* B2, int M) {
  __shared__ ushort sA[2][GBM * 32];
  __shared__ ushort sB[2][HID * 32];
  int blk = (int)(((long long)blockIdx.x * 101) % FA_T);
  if (blk < GBLK) {
    gemm_fused_body(blk, 0, xs, offs_st, adj_st, B2, xt, wt0, wt1, b_st,
                    B2, M, &sA[0][0], &sB[0][0]);
  } else {
    gemm_fused_body(blk - GBLK, 1, xt, offs_ts, adj_ts, B0, xs, wt2, wt3, b_ts,
                    B0, M, &sA[0][0], &sB[0][0]);
  }
}

// ---------------------------------------------------------------------------
// Launch B: gemm3_f (782): gather_ts(t1=B2) -> bounce B1 -> s2 -> xs (dead)
// ---------------------------------------------------------------------------
__global__ __launch_bounds__(256, 4) void gemm_fused3(
    const ushort* __restrict__ t1,
    const int* __restrict__ offs_ts, const int* __restrict__ adj_ts,
    ushort* B1, const ushort* __restrict__ s1,
    const ushort* __restrict__ wt4, const ushort* __restrict__ wt5,
    const float* __restrict__ bias, ushort* C, int M) {
  __shared__ ushort sA[2][GBM * 32];
  __shared__ ushort sB[2][HID * 32];
  gemm_fused_body(blockIdx.x, 2, t1, offs_ts, adj_ts, B1, s1, wt4, wt5, bias,
                  C, M, &sA[0][0], &sB[0][0]);
}

// ---------------------------------------------------------------------------
// Final projection: [M,256] bf16 @ [256,16] fp32 + bout -> fp32
// ---------------------------------------------------------------------------
__global__ __launch_bounds__(256) void out_gemm_h(const ushort* __restrict__ X,
                                                  const float* __restrict__ Wout,
                                                  const float* __restrict__ bout,
                                                  float* __restrict__ C, int M) {
  __shared__ float sW[DIN * DOUT];
  int tid = threadIdx.x;
#pragma unroll
  for (int i = 0; i < (DIN * DOUT) / 256; ++i) sW[i * 256 + tid] = Wout[i * 256 + tid];
  __syncthreads();
  int rr = tid >> 4, c = tid & 15;
  int row = blockIdx.x * 16 + rr;
  if (row >= M) return;
  float acc = bout[c];
  const ushort* xp = X + (size_t)row * DIN;
  for (int k = 0; k < DIN; k += 8) {
    uint4 u = *(const uint4*)(xp + k);
    const ushort* us = (const ushort*)&u;
#pragma unroll
    for (int t = 0; t < 8; ++t) acc += b2f(us[t]) * sW[(k + t) * DOUT + c];
  }
  C[(size_t)row * DOUT + c] = acc;
}

// ---------------------------------------------------------------------------
// Workspace (~133 MB, masks array removed)
// ---------------------------------------------------------------------------
extern "C" void kernel_launch(void* const* d_in, const int* in_sizes, int n_in,
                              void* d_out, int out_size, void* d_ws, size_t ws_size,
                              hipStream_t stream) {
  const float* x_source = (const float*)d_in[0];
  const float* x_target = (const float*)d_in[1];
  const int* ei_st = (const int*)d_in[2];
  const int* ei_ts = (const int*)d_in[3];
  const float* Wl_st = (const float*)d_in[4];
  const float* Wr_st = (const float*)d_in[5];
  const float* b_st  = (const float*)d_in[6];
  const float* Wl_ts = (const float*)d_in[7];
  const float* Wr_ts = (const float*)d_in[8];
  const float* b_ts  = (const float*)d_in[9];
  const float* Wout  = (const float*)d_in[10];
  const float* bout  = (const float*)d_in[11];
  float* out = (float*)d_out;

  const size_t F = (size_t)NSRC * DIN;  // 12.8M elements
  const size_t WM = (size_t)DIN * HID;  // 65536
  const int nbScan = (NSRC + SB - 1) / SB;  // 49 (NSRC==NTGT)
  const size_t intCount = (NTGT + 1) + (NSRC + 1) + 2 * NE + NTGT + NSRC +
                          2 * nbScan;
  const size_t need = (5 * F + 6 * WM) * sizeof(ushort) + intCount * sizeof(int);
  if (ws_size < need) return;

  ushort* xs0h = (ushort*)d_ws;
  ushort* xt0h = xs0h + F;
  ushort* B0h  = xt0h + F;
  ushort* B1h  = B0h + F;
  ushort* B2h  = B1h + F;
  ushort* wt0  = B2h + F;       // Wl_st[0]^T
  ushort* wt1  = wt0 + WM;      // Wr_st[0]^T
  ushort* wt2  = wt1 + WM;      // Wl_ts[0]^T
  ushort* wt3  = wt2 + WM;      // Wr_ts[0]^T
  ushort* wt4  = wt3 + WM;      // Wl_ts[1]^T
  ushort* wt5  = wt4 + WM;      // Wr_ts[1]^T
  int* ip      = (int*)(wt5 + WM);
  int* offs_st = ip;
  int* offs_ts = offs_st + NTGT + 1;
  int* adj_st  = offs_ts + NSRC + 1;
  int* adj_ts  = adj_st + NE;
  int* cur_t   = adj_ts + NE;        // [NTGT] + [NSRC] adjacent for one memset
  int* cur_s   = cur_t + NTGT;
  int* bsum    = cur_s + NSRC;       // [2*nbScan]

  const int EB = (NE + 255) / 256;   // 1250

  // ---- Phase 0: zero the histograms, then all independent prep work ----
  (void)hipMemsetAsync(cur_t, 0, (NTGT + NSRC) * sizeof(int), stream);
  PrepArgs pa;
  pa.xs = x_source; pa.xt = x_target; pa.oxs = xs0h; pa.oxt = xt0h;
  pa.wsrc[0] = Wl_st;      pa.wdst[0] = wt0;
  pa.wsrc[1] = Wr_st;      pa.wdst[1] = wt1;
  pa.wsrc[2] = Wl_ts;      pa.wdst[2] = wt2;
  pa.wsrc[3] = Wr_ts;      pa.wdst[3] = wt3;
  pa.wsrc[4] = Wl_ts + WM; pa.wdst[4] = wt4;
  pa.wsrc[5] = Wr_ts + WM; pa.wdst[5] = wt5;
  pa.ei_a = ei_st; pa.ei_b = ei_ts;
  pa.cur_a = cur_t; pa.cur_b = cur_s;
  prep_kernel<<<PREP_T, 256, 0, stream>>>(pa);

  // ---- CSR scan + fill ----
  scan_partial<<<2 * nbScan, SB, 0, stream>>>(cur_t, cur_s, bsum, NTGT, nbScan);
  scan_base<<<1, 128, 0, stream>>>(bsum, nbScan);
  scan_final<<<2 * nbScan, SB, 0, stream>>>(cur_t, cur_s, offs_st, offs_ts,
                                            bsum, NTGT, nbScan);
  csr_fill2<<<2 * EB, 256, 0, stream>>>(ei_st, ei_ts, offs_st, offs_ts,
                                        cur_t, cur_s, adj_st, adj_ts, NE, EB);

  // ---- Launch A: gemm1_f (t1 -> B2h) + gemm2_f (s1 -> B0h), fused gathers,
  //      inline masks ----
  gemm_fused12<<<FA_T, 256, 0, stream>>>(
      xs0h, xt0h, offs_st, adj_st, offs_ts, adj_ts,
      wt0, wt1, wt2, wt3, b_st, b_ts, B0h, B2h, NSRC);

  // ---- Launch B: gemm3_f (s2 -> xs0h), fused L1 gather over t1=B2h ----
  gemm_fused3<<<GBLK, 256, 0, stream>>>(
      B2h, offs_ts, adj_ts, B1h, B0h, wt4, wt5, b_ts + HID, xs0h, NSRC);

  out_gemm_h<<<(NSRC + 15) / 16, 256, 0, stream>>>(xs0h, Wout, bout, out, NSRC);
}

// Round 7
// 438.455 us; speedup vs baseline: 1.8585x; 1.8585x over previous
//
#include <hip/hip_runtime.h>
#include <stdint.h>

// Problem constants (fixed by reference)
#define NSRC 50000
#define NTGT 50000
#define NE   320000
#define DIN  256
#define HID  256
#define DOUT 16

#define GBM 64
#define GBLK ((NSRC + GBM - 1) / GBM)      // 782 gemm blocks
#define MASK_DW_PER (GBLK * 512)           // 400384 mask dwords per gemm

typedef __attribute__((ext_vector_type(8))) short bf16x8;
typedef __attribute__((ext_vector_type(4))) float f32x4;
typedef __attribute__((ext_vector_type(4))) uint u32x4;

// ---------------------------------------------------------------------------
// bf16 <-> f32 (RNE, matches HW/XLA rounding)
// ---------------------------------------------------------------------------
__device__ inline ushort f2b(float f) {
  uint32_t u = __float_as_uint(f);
  return (ushort)((u + 0x7FFFu + ((u >> 16) & 1u)) >> 16);
}
__device__ inline float b2f(ushort h) { return __uint_as_float(((uint32_t)h) << 16); }

// ---------------------------------------------------------------------------
// Async global->LDS 16B copy: lane deposits 16 B at lds_base + lane*16.
// ---------------------------------------------------------------------------
typedef __attribute__((address_space(3))) uint32_t lds_u32_t;
typedef const __attribute__((address_space(1))) uint32_t glb_u32_t;
__device__ __forceinline__ void ld_lds16(const ushort* g, ushort* lds) {
  __builtin_amdgcn_global_load_lds((glb_u32_t*)g, (lds_u32_t*)lds, 16, 0, 0);
}

// ---------------------------------------------------------------------------
// Threefry-2x32 (exact JAX: 20 rounds, 5 key injections) — verified R2
// ---------------------------------------------------------------------------
__host__ __device__ constexpr uint64_t tf2x32(uint32_t k0, uint32_t k1,
                                              uint32_t x0, uint32_t x1) {
  uint32_t ks2 = k0 ^ k1 ^ 0x1BD11BDAu;
  x0 += k0; x1 += k1;
#define TF_ROT(x, r) (((x) << (r)) | ((x) >> (32 - (r))))
#define TF_RND(r) { x0 += x1; x1 = TF_ROT(x1, r) ^ x0; }
  TF_RND(13) TF_RND(15) TF_RND(26) TF_RND(6)
  x0 += k1;  x1 += ks2 + 1u;
  TF_RND(17) TF_RND(29) TF_RND(16) TF_RND(24)
  x0 += ks2; x1 += k0 + 2u;
  TF_RND(13) TF_RND(15) TF_RND(26) TF_RND(6)
  x0 += k0;  x1 += k1 + 3u;
  TF_RND(17) TF_RND(29) TF_RND(16) TF_RND(24)
  x0 += k1;  x1 += ks2 + 4u;
  TF_RND(13) TF_RND(15) TF_RND(26) TF_RND(6)
  x0 += ks2; x1 += k0 + 5u;
#undef TF_RND
#undef TF_ROT
  return (uint64_t(x0) << 32) | uint64_t(x1);
}

constexpr uint64_t FOLD[4] = {
  tf2x32(0u, 42u, 0u, 0u),
  tf2x32(0u, 42u, 0u, 1u),
  tf2x32(0u, 42u, 0u, 2u),
  tf2x32(0u, 42u, 0u, 3u),
};

// ---------------------------------------------------------------------------
// Dropout keep-mask word for mask-dword index d (bit layout mirrors the gemm
// epilogue; verified bit-identical R8-R10). Keep: bits>>9 < 7549747
// (== 0.9f * 2^23, exact).
// ---------------------------------------------------------------------------
__device__ __forceinline__ void mask_word(uint32_t* __restrict__ masks, int d) {
  int g = d / MASK_DW_PER;                            // 0..2
  int w = d - g * MASK_DW_PER;
  int gt = w >> 1, half = w & 1;
  int gblk = gt >> 8, gtid = gt & 255;
  int wave = gtid >> 6, lane = gtid & 63;
  int q = lane >> 4, r = lane & 15;
  uint64_t fk = (g == 0) ? FOLD[1] : (g == 1 ? FOLD[0] : FOLD[2]);
  uint32_t kk0 = (uint32_t)(fk >> 32), kk1 = (uint32_t)fk;
  int mbase = gblk * GBM;
  uint32_t mword = 0;
#pragma unroll
  for (int bb = 0; bb < 32; ++bb) {
    int s = half * 32 + bb;
    int si = s >> 4, se = (s >> 2) & 3, sj = s & 3;
    uint32_t rowg = (uint32_t)(mbase + si * 16 + q * 4 + se);
    uint32_t colg = (uint32_t)(wave * 64 + sj * 16 + r);
    uint64_t rr = tf2x32(kk0, kk1, 0u, rowg * 256u + colg);
    uint32_t bits = (uint32_t)(rr >> 32) ^ (uint32_t)rr;
    mword |= (((bits >> 9) < 7549747u) ? 1u : 0u) << bb;
  }
  masks[d] = mword;
}

// ---------------------------------------------------------------------------
// prep_kernel: independent front work:
//   [0, 25000)        f32->bf16 conversion of both inputs  (memory-bound)
//   [25000, 25096)    6 weight transpose+converts           (memory-bound)
//   [25096, 27596)    2 CSR histograms                      (atomic-bound)
// ---------------------------------------------------------------------------
#define NB_CVT  25000
#define NB_W    96
#define NB_HIST 2500
#define PREP_T  (NB_CVT + NB_W + NB_HIST)  // 27596

struct PrepArgs {
  const float *xs, *xt;
  ushort *oxs, *oxt;
  const float* wsrc[6];
  ushort* wdst[6];
  const int *ei_a, *ei_b;
  int *cur_a, *cur_b;
};

__global__ __launch_bounds__(256) void prep_kernel(PrepArgs p) {
  __shared__ ushort tile[64][65];
  int blk = (int)(((long long)blockIdx.x * 97) % PREP_T);
  int tid = threadIdx.x;
  if (blk < NB_CVT) {  // input conversion
    const float* in = blk < (NB_CVT / 2) ? p.xs : p.xt;
    ushort* out = blk < (NB_CVT / 2) ? p.oxs : p.oxt;
    int i = (blk % (NB_CVT / 2)) * 256 + tid;
    float4 v = ((const float4*)in)[i];
    ushort4 o;
    o.x = f2b(v.x); o.y = f2b(v.y); o.z = f2b(v.z); o.w = f2b(v.w);
    ((ushort4*)out)[i] = o;
    return;
  }
  blk -= NB_CVT;
  if (blk < NB_W) {  // weight transpose: fp32 [k][n] -> bf16 [n][k]
    const float* W = p.wsrc[blk >> 4];
    ushort* Wt = p.wdst[blk >> 4];
    int ktile = (blk >> 2) & 3, ntile = blk & 3;
#pragma unroll
    for (int rep = 0; rep < 16; ++rep) {
      int lin = rep * 256 + tid;
      int kk = lin >> 6, nn = lin & 63;
      tile[nn][kk] = f2b(W[(size_t)(ktile * 64 + kk) * 256 + ntile * 64 + nn]);
    }
    __syncthreads();
#pragma unroll
    for (int rep = 0; rep < 16; ++rep) {
      int lin = rep * 256 + tid;
      int nn = lin >> 6, kk = lin & 63;
      Wt[(size_t)(ntile * 64 + nn) * 256 + ktile * 64 + kk] = tile[nn][kk];
    }
    return;
  }
  blk -= NB_W;
  // CSR histogram
  const int* ei = blk < (NB_HIST / 2) ? p.ei_a : p.ei_b;
  int* cur = blk < (NB_HIST / 2) ? p.cur_a : p.cur_b;
  int e = (blk % (NB_HIST / 2)) * 256 + tid;
  if (e < NE) atomicAdd(cur + ei[NE + e], 1);
}

// ---------------------------------------------------------------------------
// CSR scan + fill (two-level scan, verified R6)
// ---------------------------------------------------------------------------
#define SB 1024
__global__ __launch_bounds__(SB) void scan_partial(const int* __restrict__ cur_a,
                                                   const int* __restrict__ cur_b,
                                                   int* __restrict__ bsum,
                                                   int n, int nbPer) {
  __shared__ int red[SB];
  int b = blockIdx.x;
  const int* cnt = b < nbPer ? cur_a : cur_b;
  int i = (b % nbPer) * SB + threadIdx.x;
  red[threadIdx.x] = (i < n) ? cnt[i] : 0;
  __syncthreads();
  for (int d = SB / 2; d > 0; d >>= 1) {
    if (threadIdx.x < d) red[threadIdx.x] += red[threadIdx.x + d];
    __syncthreads();
  }
  if (threadIdx.x == 0) bsum[b] = red[0];
}

__global__ __launch_bounds__(128) void scan_base(int* __restrict__ bsum, int nbPer) {
  __shared__ int buf[2][64];
  int half = threadIdx.x >> 6;
  int t = threadIdx.x & 63;
  buf[half][t] = (t < nbPer) ? bsum[half * nbPer + t] : 0;
  __syncthreads();
  for (int d = 1; d < 64; d <<= 1) {
    int v = (t >= d) ? buf[half][t - d] : 0;
    __syncthreads();
    buf[half][t] += v;
    __syncthreads();
  }
  if (t < nbPer) bsum[half * nbPer + t] = (t == 0) ? 0 : buf[half][t - 1];
}

__global__ __launch_bounds__(SB) void scan_final(int* __restrict__ cur_a,
                                                 int* __restrict__ cur_b,
                                                 int* __restrict__ offs_a,
                                                 int* __restrict__ offs_b,
                                                 const int* __restrict__ bsum,
                                                 int n, int nbPer) {
  __shared__ int part[SB];
  int b = blockIdx.x;
  bool first = b < nbPer;
  int* cur = first ? cur_a : cur_b;
  int* offs = first ? offs_a : offs_b;
  int i = (b % nbPer) * SB + threadIdx.x;
  int v = (i < n) ? cur[i] : 0;
  part[threadIdx.x] = v;
  __syncthreads();
  for (int d = 1; d < SB; d <<= 1) {
    int tv = (threadIdx.x >= d) ? part[threadIdx.x - d] : 0;
    __syncthreads();
    part[threadIdx.x] += tv;
    __syncthreads();
  }
  int excl = part[threadIdx.x] - v + bsum[b];
  if (i < n) {
    offs[i] = excl;
    cur[i] = 0;
  }
  if (i == n - 1) offs[n] = excl + v;
}

__global__ __launch_bounds__(256) void csr_fill2(const int* __restrict__ ei_a,
                                                 const int* __restrict__ ei_b,
                                                 const int* __restrict__ offs_a,
                                                 const int* __restrict__ offs_b,
                                                 int* __restrict__ cur_a,
                                                 int* __restrict__ cur_b,
                                                 int* __restrict__ adj_a,
                                                 int* __restrict__ adj_b,
                                                 int nE, int nbPer) {
  int blk = blockIdx.x;
  bool first = blk < nbPer;
  const int* ei = first ? ei_a : ei_b;
  const int* offs = first ? offs_a : offs_b;
  int* cur = first ? cur_a : cur_b;
  int* adj = first ? adj_a : adj_b;
  int e = (blk % nbPer) * 256 + threadIdx.x;
  if (e >= nE) return;
  int dst = ei[nE + e];
  int pos = atomicAdd(cur + dst, 1);
  adj[offs[dst] + pos] = ei[e];
}

// ---------------------------------------------------------------------------
// Segment-mean gather: 32 lanes per row (16B loads), 2 rows per wave, 8 rows
// per block. R13: 8-edge unrolled main loop (8 outstanding 16B loads/lane)
// for deeper memory-level parallelism; per-feature accumulation order stays
// ascending-edge -> bit-identical.
// ---------------------------------------------------------------------------
#define ACC8(vv)                                                              \
  {                                                                           \
    const ushort* u = (const ushort*)&vv;                                     \
    a0 += b2f(u[0]); a1 += b2f(u[1]); a2 += b2f(u[2]); a3 += b2f(u[3]);       \
    a4 += b2f(u[4]); a5 += b2f(u[5]); a6 += b2f(u[6]); a7 += b2f(u[7]);       \
  }

__device__ __forceinline__ void gather_row8(const ushort* __restrict__ x,
                                            const int* __restrict__ offs,
                                            const int* __restrict__ adj,
                                            ushort* __restrict__ m,
                                            int row, int lane) {  // lane 0..31
  int start = offs[row], end = offs[row + 1];
  float a0 = 0.f, a1 = 0.f, a2 = 0.f, a3 = 0.f;
  float a4 = 0.f, a5 = 0.f, a6 = 0.f, a7 = 0.f;
  const ushort* xb = x + lane * 8;
  int e = start;
  for (; e + 7 < end; e += 8) {
    int s0 = adj[e],     s1 = adj[e + 1], s2 = adj[e + 2], s3 = adj[e + 3];
    int s4 = adj[e + 4], s5 = adj[e + 5], s6 = adj[e + 6], s7 = adj[e + 7];
    u32x4 v0 = *(const u32x4*)(xb + (size_t)s0 * DIN);
    u32x4 v1 = *(const u32x4*)(xb + (size_t)s1 * DIN);
    u32x4 v2 = *(const u32x4*)(xb + (size_t)s2 * DIN);
    u32x4 v3 = *(const u32x4*)(xb + (size_t)s3 * DIN);
    u32x4 v4 = *(const u32x4*)(xb + (size_t)s4 * DIN);
    u32x4 v5 = *(const u32x4*)(xb + (size_t)s5 * DIN);
    u32x4 v6 = *(const u32x4*)(xb + (size_t)s6 * DIN);
    u32x4 v7 = *(const u32x4*)(xb + (size_t)s7 * DIN);
    ACC8(v0) ACC8(v1) ACC8(v2) ACC8(v3) ACC8(v4) ACC8(v5) ACC8(v6) ACC8(v7)
  }
  for (; e + 3 < end; e += 4) {
    int s0 = adj[e], s1 = adj[e + 1], s2 = adj[e + 2], s3 = adj[e + 3];
    u32x4 v0 = *(const u32x4*)(xb + (size_t)s0 * DIN);
    u32x4 v1 = *(const u32x4*)(xb + (size_t)s1 * DIN);
    u32x4 v2 = *(const u32x4*)(xb + (size_t)s2 * DIN);
    u32x4 v3 = *(const u32x4*)(xb + (size_t)s3 * DIN);
    ACC8(v0) ACC8(v1) ACC8(v2) ACC8(v3)
  }
  for (; e < end; ++e) {
    int s = adj[e];
    u32x4 v = *(const u32x4*)(xb + (size_t)s * DIN);
    ACC8(v)
  }
  float inv = 1.0f / fmaxf((float)(end - start), 1.0f);
  ushort o[8];
  o[0] = f2b(a0 * inv); o[1] = f2b(a1 * inv); o[2] = f2b(a2 * inv); o[3] = f2b(a3 * inv);
  o[4] = f2b(a4 * inv); o[5] = f2b(a5 * inv); o[6] = f2b(a6 * inv); o[7] = f2b(a7 * inv);
  *(u32x4*)(m + (size_t)row * DIN + lane * 8) = *(const u32x4*)o;
}

// ---------------------------------------------------------------------------
// Launch A: st-relation gather (B0h) + dropout-mask slices 0,1.
// ---------------------------------------------------------------------------
#define GG_GB 6250                          // gather blocks per relation (8 rows/blk)
#define G2_MASKB (2 * MASK_DW_PER / 256)    // 3128 mask blocks (slices 0,1)
#define GM_T (GG_GB + G2_MASKB)             // 9378 = 2*3*3*521; 97 coprime

__global__ __launch_bounds__(256) void gather_mask_h(
    const ushort* __restrict__ x, const int* __restrict__ offs,
    const int* __restrict__ adj, ushort* __restrict__ m,
    uint32_t* __restrict__ masks, int nRows) {
  int blk = (int)(((long long)blockIdx.x * 97) % GM_T);
  int tid = threadIdx.x;
  if (blk >= GG_GB) {  // mask-gen blocks: dwords [0, 2*MASK_DW_PER)
    mask_word(masks, (blk - GG_GB) * 256 + tid);
    return;
  }
  int row = blk * 8 + (tid >> 5);
  if (row < nRows) gather_row8(x, offs, adj, m, row, tid & 31);
}

// ---------------------------------------------------------------------------
// MFMA dual GEMM K-loop (verified R8-R10): acc = A1@W1 + A2@W2 (bf16 MFMA,
// f32 acc). Async global_load_lds staging; 40KB LDS footprint.
// ---------------------------------------------------------------------------
__device__ __forceinline__ void gemm_kloop(
    int bid, const ushort* __restrict__ A1, const ushort* __restrict__ A2,
    const ushort* __restrict__ W1t, const ushort* __restrict__ W2t,
    int M, ushort* sA, ushort* sB, f32x4 acc[4][4]) {
  const int tid = threadIdx.x;
  const int wave = tid >> 6, lane = tid & 63;
  const int q = lane >> 4, r = lane & 15;
  const int mbase = bid * GBM;

  const int arow = tid >> 2;        // 0..63
  const int akc = (tid & 3) * 8;    // short offset 0,8,16,24
  const int agrow = min(mbase + arow, M - 1);
  const ushort* a1p = A1 + (size_t)agrow * DIN + akc;
  const ushort* a2p = A2 + (size_t)agrow * DIN + akc;
  const ushort* w1b = W1t + (size_t)arow * DIN + akc;
  const ushort* w2b = W2t + (size_t)arow * DIN + akc;
  ushort* ldsA0 = sA + wave * 512;              // sA phase 0
  ushort* ldsA1 = sA + 2048 + wave * 512;       // sA phase 1

#pragma unroll
  for (int t = 0; t < 8; ++t) {
    const int kt = t * 32;
    __syncthreads();  // prior iter's LDS reads done before DMA overwrites
    ld_lds16(a1p + kt, ldsA0);
    ld_lds16(a2p + kt, ldsA1);
#pragma unroll
    for (int c = 0; c < 4; ++c) {
      ld_lds16(w1b + c * (64 * DIN) + kt, sB + c * 2048 + wave * 512);
      ld_lds16(w2b + c * (64 * DIN) + kt, sB + 8192 + c * 2048 + wave * 512);
    }
    __syncthreads();  // drains vmcnt(0): DMA complete
#pragma unroll
    for (int ph = 0; ph < 2; ++ph) {
      bf16x8 af[4], bfr[4];
#pragma unroll
      for (int i = 0; i < 4; ++i)
        af[i] = *(const bf16x8*)&sA[ph * 2048 + (i * 16 + r) * 32 + q * 8];
#pragma unroll
      for (int j = 0; j < 4; ++j)
        bfr[j] = *(const bf16x8*)&sB[ph * 8192 + (wave * 64 + j * 16 + r) * 32 + q * 8];
#pragma unroll
      for (int i = 0; i < 4; ++i)
#pragma unroll
        for (int j = 0; j < 4; ++j)
          acc[i][j] = __builtin_amdgcn_mfma_f32_16x16x32_bf16(af[i], bfr[j],
                                                              acc[i][j], 0, 0, 0);
    }
  }
}

// Standard epilogue: bias + leaky + masked dropout scale + bf16 store to C.
__device__ __forceinline__ void gemm_body(
    int bid, const ushort* __restrict__ A1, const ushort* __restrict__ A2,
    const ushort* __restrict__ W1t, const ushort* __restrict__ W2t,
    const float* __restrict__ bias, const uint2* __restrict__ mk,
    ushort* __restrict__ C, int M, ushort* sA, ushort* sB) {
  const int tid = threadIdx.x;
  const int wave = tid >> 6, lane = tid & 63;
  const int q = lane >> 4, r = lane & 15;
  const int mbase = bid * GBM;
  const uint2 km = mk[bid * 256 + tid];  // issued early, hidden by K-loop

  f32x4 acc[4][4] = {};
  gemm_kloop(bid, A1, A2, W1t, W2t, M, sA, sB, acc);

  float bj[4];
#pragma unroll
  for (int j = 0; j < 4; ++j) bj[j] = bias[wave * 64 + j * 16 + r];
#pragma unroll
  for (int i = 0; i < 4; ++i) {
#pragma unroll
    for (int e = 0; e < 4; ++e) {
      int rowg = mbase + i * 16 + q * 4 + e;
      if (rowg >= M) continue;
#pragma unroll
      for (int j = 0; j < 4; ++j) {
        const int s = i * 16 + e * 4 + j;
        int colg = wave * 64 + j * 16 + r;
        float v = acc[i][j][e] + bj[j];
        v = v >= 0.0f ? v : 0.01f * v;
        uint32_t keep = ((s < 32 ? km.x >> s : km.y >> (s - 32)) & 1u);
        v = keep ? v * (1.0f / 0.9f) : 0.0f;
        C[(size_t)rowg * HID + colg] = f2b(v);
      }
    }
  }
}

__global__ __launch_bounds__(256, 4) void gemm_dual_mfma(
    const ushort* __restrict__ A1, const ushort* __restrict__ A2,
    const ushort* __restrict__ W1t, const ushort* __restrict__ W2t,
    const float* __restrict__ bias, const uint2* __restrict__ mk,
    ushort* __restrict__ C, int M) {
  __shared__ ushort sA[2][GBM * 32];
  __shared__ ushort sB[2][HID * 32];
  gemm_body(blockIdx.x, A1, A2, W1t, W2t, bias, mk, C, M, &sA[0][0], &sB[0][0]);
}

// ---------------------------------------------------------------------------
// Launch B: gemm1 (782) + ts-relation gather (6250) + mask slice 2 (1564,
// consumed only by gemm3 two launches later). G1_T = 8596 = 2^2*7*307;
// 101 coprime.
// ---------------------------------------------------------------------------
#define GG_MASKB (MASK_DW_PER / 256)          // 1564 mask blocks (slice 2)
#define G1_T (GBLK + GG_GB + GG_MASKB)        // 8596

__global__ __launch_bounds__(256, 4) void gemm1_gather(
    const ushort* __restrict__ A1, const ushort* __restrict__ A2,
    const ushort* __restrict__ W1t, const ushort* __restrict__ W2t,
    const float* __restrict__ bias, const uint2* __restrict__ mk,
    ushort* __restrict__ C, int M,
    const ushort* __restrict__ gx, const int* __restrict__ goffs,
    const int* __restrict__ gadj, ushort* __restrict__ gm, int gRows,
    uint32_t* __restrict__ masks) {
  __shared__ ushort sA[2][GBM * 32];
  __shared__ ushort sB[2][HID * 32];
  int blk = (int)(((long long)blockIdx.x * 101) % G1_T);
  if (blk < GBLK) {
    gemm_body(blk, A1, A2, W1t, W2t, bias, mk, C, M, &sA[0][0], &sB[0][0]);
  } else if (blk < GBLK + GG_GB) {
    int row = (blk - GBLK) * 8 + (threadIdx.x >> 5);
    if (row < gRows) gather_row8(gx, goffs, gadj, gm, row, threadIdx.x & 31);
  } else {
    // mask slice 2: dwords [2*MASK_DW_PER, 3*MASK_DW_PER)
    mask_word(masks,
              2 * MASK_DW_PER + (blk - GBLK - GG_GB) * 256 + (int)threadIdx.x);
  }
}

// ---------------------------------------------------------------------------
// Launch C: gemm2 (782) + L1 gather (6250), one swizzled launch.
// GG_T = 7032 = 2^3*3*293; 101 coprime.
// ---------------------------------------------------------------------------
#define GG_T  (GBLK + GG_GB)                  // 7032

__global__ __launch_bounds__(256, 4) void gemm_gather(
    const ushort* __restrict__ A1, const ushort* __restrict__ A2,
    const ushort* __restrict__ W1t, const ushort* __restrict__ W2t,
    const float* __restrict__ bias, const uint2* __restrict__ mk,
    ushort* __restrict__ C, int M,
    const ushort* __restrict__ gx, const int* __restrict__ goffs,
    const int* __restrict__ gadj, ushort* __restrict__ gm, int gRows) {
  __shared__ ushort sA[2][GBM * 32];
  __shared__ ushort sB[2][HID * 32];
  int blk = (int)(((long long)blockIdx.x * 101) % GG_T);
  if (blk < GBLK) {
    gemm_body(blk, A1, A2, W1t, W2t, bias, mk, C, M, &sA[0][0], &sB[0][0]);
  } else {
    int row = (blk - GBLK) * 8 + (threadIdx.x >> 5);
    if (row < gRows) gather_row8(gx, goffs, gadj, gm, row, threadIdx.x & 31);
  }
}

// ---------------------------------------------------------------------------
// Final projection: [M,256] bf16 @ [256,16] fp32 + bout -> fp32
// ---------------------------------------------------------------------------
__global__ __launch_bounds__(256) void out_gemm_h(const ushort* __restrict__ X,
                                                  const float* __restrict__ Wout,
                                                  const float* __restrict__ bout,
                                                  float* __restrict__ C, int M) {
  __shared__ float sW[DIN * DOUT];
  int tid = threadIdx.x;
#pragma unroll
  for (int i = 0; i < (DIN * DOUT) / 256; ++i) sW[i * 256 + tid] = Wout[i * 256 + tid];
  __syncthreads();
  int rr = tid >> 4, c = tid & 15;
  int row = blockIdx.x * 16 + rr;
  if (row >= M) return;
  float acc = bout[c];
  const ushort* xp = X + (size_t)row * DIN;
  for (int k = 0; k < DIN; k += 8) {
    uint4 u = *(const uint4*)(xp + k);
    const ushort* us = (const ushort*)&u;
#pragma unroll
    for (int t = 0; t < 8; ++t) acc += b2f(us[t]) * sW[(k + t) * DOUT + c];
  }
  C[(size_t)row * DOUT + c] = acc;
}

// ---------------------------------------------------------------------------
// Workspace (~138 MB < 154 MB proven safe)
// ---------------------------------------------------------------------------
extern "C" void kernel_launch(void* const* d_in, const int* in_sizes, int n_in,
                              void* d_out, int out_size, void* d_ws, size_t ws_size,
                              hipStream_t stream) {
  const float* x_source = (const float*)d_in[0];
  const float* x_target = (const float*)d_in[1];
  const int* ei_st = (const int*)d_in[2];
  const int* ei_ts = (const int*)d_in[3];
  const float* Wl_st = (const float*)d_in[4];
  const float* Wr_st = (const float*)d_in[5];
  const float* b_st  = (const float*)d_in[6];
  const float* Wl_ts = (const float*)d_in[7];
  const float* Wr_ts = (const float*)d_in[8];
  const float* b_ts  = (const float*)d_in[9];
  const float* Wout  = (const float*)d_in[10];
  const float* bout  = (const float*)d_in[11];
  float* out = (float*)d_out;

  const size_t F = (size_t)NSRC * DIN;  // 12.8M elements
  const size_t WM = (size_t)DIN * HID;  // 65536
  const int nbScan = (NSRC + SB - 1) / SB;  // 49 (NSRC==NTGT)
  const size_t intCount = (NTGT + 1) + (NSRC + 1) + 2 * NE + NTGT + NSRC +
                          2 * nbScan + 3 * MASK_DW_PER;
  const size_t need = (5 * F + 6 * WM) * sizeof(ushort) + intCount * sizeof(int);
  if (ws_size < need) return;

  ushort* xs0h = (ushort*)d_ws;
  ushort* xt0h = xs0h + F;
  ushort* B0h  = xt0h + F;
  ushort* B1h  = B0h + F;
  ushort* B2h  = B1h + F;
  ushort* wt0  = B2h + F;       // Wl_st[0]^T
  ushort* wt1  = wt0 + WM;      // Wr_st[0]^T
  ushort* wt2  = wt1 + WM;      // Wl_ts[0]^T
  ushort* wt3  = wt2 + WM;      // Wr_ts[0]^T
  ushort* wt4  = wt3 + WM;      // Wl_ts[1]^T
  ushort* wt5  = wt4 + WM;      // Wr_ts[1]^T
  int* ip      = (int*)(wt5 + WM);
  int* offs_st = ip;
  int* offs_ts = offs_st + NTGT + 1;
  int* adj_st  = offs_ts + NSRC + 1;
  int* adj_ts  = adj_st + NE;
  int* cur_t   = adj_ts + NE;        // [NTGT] + [NSRC] adjacent for one memset
  int* cur_s   = cur_t + NTGT;
  int* bsum    = cur_s + NSRC;       // [2*nbScan]
  uint32_t* masks = (uint32_t*)(bsum + 2 * nbScan);  // [3*MASK_DW_PER]

  const int EB = (NE + 255) / 256;   // 1250

  // ---- Phase 0: zero the histograms, then all independent prep work ----
  (void)hipMemsetAsync(cur_t, 0, (NTGT + NSRC) * sizeof(int), stream);
  PrepArgs pa;
  pa.xs = x_source; pa.xt = x_target; pa.oxs = xs0h; pa.oxt = xt0h;
  pa.wsrc[0] = Wl_st;      pa.wdst[0] = wt0;
  pa.wsrc[1] = Wr_st;      pa.wdst[1] = wt1;
  pa.wsrc[2] = Wl_ts;      pa.wdst[2] = wt2;
  pa.wsrc[3] = Wr_ts;      pa.wdst[3] = wt3;
  pa.wsrc[4] = Wl_ts + WM; pa.wdst[4] = wt4;
  pa.wsrc[5] = Wr_ts + WM; pa.wdst[5] = wt5;
  pa.ei_a = ei_st; pa.ei_b = ei_ts;
  pa.cur_a = cur_t; pa.cur_b = cur_s;
  prep_kernel<<<PREP_T, 256, 0, stream>>>(pa);

  // ---- CSR scan + fill ----
  scan_partial<<<2 * nbScan, SB, 0, stream>>>(cur_t, cur_s, bsum, NTGT, nbScan);
  scan_base<<<1, 128, 0, stream>>>(bsum, nbScan);
  scan_final<<<2 * nbScan, SB, 0, stream>>>(cur_t, cur_s, offs_st, offs_ts,
                                            bsum, NTGT, nbScan);
  csr_fill2<<<2 * EB, 256, 0, stream>>>(ei_st, ei_ts, offs_st, offs_ts,
                                        cur_t, cur_s, adj_st, adj_ts, NE, EB);

  // ---- Launch A: st-gather (-> B0h) + mask slices 0,1 ----
  gather_mask_h<<<GM_T, 256, 0, stream>>>(xs0h, offs_st, adj_st, B0h,
                                          masks, NTGT);

  // ---- Launch B: gemm1 (new_t -> B2h, slice 0) + ts-gather (-> B1h)
  //      + mask slice 2 ----
  gemm1_gather<<<G1_T, 256, 0, stream>>>(
      B0h, xt0h, wt0, wt1, b_st, (const uint2*)(masks), B2h, NTGT,
      xt0h, offs_ts, adj_ts, B1h, NSRC, masks);

  // ---- Launch C: gemm2 (new_s -> B0h, slice 1) + L1 gather (B2h -> xt0h) ----
  gemm_gather<<<GG_T, 256, 0, stream>>>(
      B1h, xs0h, wt2, wt3, b_ts, (const uint2*)(masks + MASK_DW_PER), B0h, NSRC,
      B2h, offs_ts, adj_ts, xt0h, NSRC);

  // ---- gemm3: L1 new_s = (m_s=xt0h, x_s(1)=B0h) -> B2h (slice 2) ----
  gemm_dual_mfma<<<GBLK, 256, 0, stream>>>(
      xt0h, B0h, wt4, wt5, b_ts + HID, (const uint2*)(masks + 2 * MASK_DW_PER),
      B2h, NSRC);

  out_gemm_h<<<(NSRC + 15) / 16, 256, 0, stream>>>(B2h, Wout, bout, out, NSRC);
}